// Round 3
// baseline (397.007 us; speedup 1.0000x reference)
//
#include <hip/hip_runtime.h>
#include <stdint.h>

#define M_TOT 8192
#define K_TOT 4096
#define N_TOT 4096
#define GROUPQ 32

#define BM 256
#define BN 256
#define BK 32
#define NT (K_TOT / BK)   // 128 K-tiles

typedef __bf16 bf16x8 __attribute__((ext_vector_type(8)));
typedef float f32x4 __attribute__((ext_vector_type(4)));
typedef unsigned short u16;
typedef unsigned short u16x8 __attribute__((ext_vector_type(8)));

__device__ __forceinline__ u16 f2bf_rne(float f) {
  union { float f; uint32_t u; } v; v.f = f;
  uint32_t u = v.u;
  uint32_t r = (u + 0x7FFFu + ((u >> 16) & 1u)) >> 16;  // round-nearest-even
  return (u16)r;
}

// ---- prepass 1: x fp32 -> bf16 ----
__global__ void cvt_x_kernel(const float* __restrict__ x, u16* __restrict__ xb, int n8) {
  int stride = gridDim.x * blockDim.x;
  for (int i = blockIdx.x * blockDim.x + threadIdx.x; i < n8; i += stride) {
    const float4* p = (const float4*)(x + (size_t)i * 8);
    float4 a = p[0];
    float4 b = p[1];
    u16x8 o;
    o[0] = f2bf_rne(a.x); o[1] = f2bf_rne(a.y); o[2] = f2bf_rne(a.z); o[3] = f2bf_rne(a.w);
    o[4] = f2bf_rne(b.x); o[5] = f2bf_rne(b.y); o[6] = f2bf_rne(b.z); o[7] = f2bf_rne(b.w);
    *(u16x8*)(xb + (size_t)i * 8) = o;
  }
}

// ---- prepass 2: dequant packed nibbles -> bf16 W[N][K] row-major ----
__global__ void dequant_w_kernel(const int* __restrict__ wp, const float* __restrict__ sc,
                                 u16* __restrict__ wb) {
  const int KH = K_TOT / 2;
  const int total = N_TOT * KH / 8;
  int stride = gridDim.x * blockDim.x;
  for (int t = blockIdx.x * blockDim.x + threadIdx.x; t < total; t += stride) {
    int base = t * 8;
    int o = base >> 11;
    int ci = base & 2047;
    int e0 = ci * 2;
    float scale = sc[o * (K_TOT / GROUPQ) + (e0 >> 5)];
    int4 p0 = *(const int4*)(wp + base);
    int4 p1 = *(const int4*)(wp + base + 4);
    int v[8] = {p0.x, p0.y, p0.z, p0.w, p1.x, p1.y, p1.z, p1.w};
    u16x8 oA, oB;
#pragma unroll
    for (int j = 0; j < 8; ++j) {
      float lo = (float)((v[j] & 0xF) - 8) * scale;
      float hi = (float)(((v[j] >> 4) & 0xF) - 8) * scale;
      u16 lob = f2bf_rne(lo), hib = f2bf_rne(hi);
      if (j < 4) { oA[2 * j] = lob; oA[2 * j + 1] = hib; }
      else       { oB[2 * (j - 4)] = lob; oB[2 * (j - 4) + 1] = hib; }
    }
    u16* dst = wb + (size_t)o * K_TOT + e0;
    *(u16x8*)dst = oA;
    *(u16x8*)(dst + 8) = oB;
  }
}

// ---- main GEMM: 256x256 tile, BK=32, 8 waves, 4-deep LDS ring (dist-3),
// one-phase-deep fragment prefetch: ds_reads for phase p+1 issued in phase p,
// serviced under phase p's MFMA via compiler counted lgkmcnt. 2 barriers/tile.
__global__ __launch_bounds__(512, 2) void gemm_bf16_kernel(
    const u16* __restrict__ A, const u16* __restrict__ Bt,
    const float* __restrict__ bias, float* __restrict__ C) {
  __shared__ alignas(16) u16 sA[4][BM * BK];  // 4 x 16 KiB
  __shared__ alignas(16) u16 sB[4][BN * BK];  // 4 x 16 KiB  (128 KiB total)

  const int ntn = N_TOT / BN;            // 16
  int wg = blockIdx.x, nwg = gridDim.x;  // 512, %8==0
  int cpx = nwg >> 3;
  int swz = (wg & 7) * cpx + (wg >> 3);  // bijective XCD swizzle
  int bm = swz / ntn, bn = swz % ntn;

  int tid = threadIdx.x, wid = tid >> 6, lane = tid & 63;
  int wr = wid >> 2, wc = wid & 3;       // 2M x 4N waves

  // ---- staging: gl_lds writes linear (base + lane*16B); source pre-swizzled
  // so LDS chunk cl holds global chunk cl ^ ((row>>1)&3) ----
  int srow0 = (wid * 2) * 16 + (lane >> 2);
  int srow1 = (wid * 2 + 1) * 16 + (lane >> 2);
  int cl = lane & 3;
  int gch0 = (cl ^ ((srow0 >> 1) & 3)) * 8;
  int gch1 = (cl ^ ((srow1 >> 1) & 3)) * 8;
  const u16* aS0 = A + (size_t)(bm * BM + srow0) * K_TOT + gch0;
  const u16* aS1 = A + (size_t)(bm * BM + srow1) * K_TOT + gch1;
  const u16* bS0 = Bt + (size_t)(bn * BN + srow0) * K_TOT + gch0;
  const u16* bS1 = Bt + (size_t)(bn * BN + srow1) * K_TOT + gch1;
  int ldst0 = (wid * 2) * 16 * BK;
  int ldst1 = (wid * 2 + 1) * 16 * BK;

  auto stageA = [&](int ke, int b) {
    __builtin_amdgcn_global_load_lds(
        (const __attribute__((address_space(1))) uint32_t*)(aS0 + ke),
        (__attribute__((address_space(3))) uint32_t*)(&sA[b][ldst0]), 16, 0, 0);
    __builtin_amdgcn_global_load_lds(
        (const __attribute__((address_space(1))) uint32_t*)(aS1 + ke),
        (__attribute__((address_space(3))) uint32_t*)(&sA[b][ldst1]), 16, 0, 0);
  };
  auto stageB = [&](int ke, int b) {
    __builtin_amdgcn_global_load_lds(
        (const __attribute__((address_space(1))) uint32_t*)(bS0 + ke),
        (__attribute__((address_space(3))) uint32_t*)(&sB[b][ldst0]), 16, 0, 0);
    __builtin_amdgcn_global_load_lds(
        (const __attribute__((address_space(1))) uint32_t*)(bS1 + ke),
        (__attribute__((address_space(3))) uint32_t*)(&sB[b][ldst1]), 16, 0, 0);
  };

  // ---- reader offsets (same involution as source) ----
  int rr = lane & 15, rc = lane >> 4;
  int xorv = (rc ^ ((rr >> 1) & 3)) * 8;
  int abase = (wr * 128 + rr) * BK + xorv;
  int bbase = (wc * 64 + rr) * BK + xorv;

  f32x4 acc[8][4] = {};

  // prologue: stage tiles 0,1,2; wait tile 0 (8 newest = tiles 1,2 in flight)
  stageA(0, 0); stageB(0, 0);
  stageA(BK, 1); stageB(BK, 1);
  stageA(2 * BK, 2); stageB(2 * BK, 2);
  asm volatile("s_waitcnt vmcnt(8)" ::: "memory");
  __builtin_amdgcn_s_barrier();

  bf16x8 afA[4], bfrA[4], afB[4], afN[4], bfrN[4];
#pragma unroll
  for (int n = 0; n < 4; ++n) bfrA[n] = *(const bf16x8*)(sB[0] + bbase + n * 16 * BK);
#pragma unroll
  for (int m = 0; m < 4; ++m) afA[m] = *(const bf16x8*)(sA[0] + abase + m * 16 * BK);

  for (int t = 0; t < NT; ++t) {
    const u16* cA = sA[t & 3];
    const u16* cB = sB[t & 3];
    const u16* nA = sA[(t + 1) & 3];
    const u16* nB = sB[(t + 1) & 3];
    int bs = (t + 3) & 3;
    int ks = ((t + 3 < NT) ? (t + 3) : (NT - 1)) * BK;  // clamped tail re-stage (dead buffer)
    (void)cB;

    // ---- P1: stage A(t+3); prefetch afB (tile t, m4..7); MFMA quad 0-3 ----
    __builtin_amdgcn_s_barrier();
    stageA(ks, bs);
#pragma unroll
    for (int m = 0; m < 4; ++m) afB[m] = *(const bf16x8*)(cA + abase + (m + 4) * 16 * BK);
    __builtin_amdgcn_s_setprio(1);
#pragma unroll
    for (int m = 0; m < 4; ++m)
#pragma unroll
      for (int n = 0; n < 4; ++n)
        acc[m][n] = __builtin_amdgcn_mfma_f32_16x16x32_bf16(afA[m], bfrA[n], acc[m][n], 0, 0, 0);
    __builtin_amdgcn_s_setprio(0);

    // ---- P2: tile t+1 guaranteed by vmcnt(6) (leaves A(t+3),B(t+2),A(t+2));
    // prefetch next-tile frags; MFMA quad 4-7 ----
    asm volatile("s_waitcnt vmcnt(6)" ::: "memory");
    __builtin_amdgcn_s_barrier();
    stageB(ks, bs);
#pragma unroll
    for (int n = 0; n < 4; ++n) bfrN[n] = *(const bf16x8*)(nB + bbase + n * 16 * BK);
#pragma unroll
    for (int m = 0; m < 4; ++m) afN[m] = *(const bf16x8*)(nA + abase + m * 16 * BK);
    __builtin_amdgcn_s_setprio(1);
#pragma unroll
    for (int m = 0; m < 4; ++m)
#pragma unroll
      for (int n = 0; n < 4; ++n)
        acc[m + 4][n] = __builtin_amdgcn_mfma_f32_16x16x32_bf16(afB[m], bfrA[n], acc[m + 4][n], 0, 0, 0);
    __builtin_amdgcn_s_setprio(0);

    // rotate fragment pipeline
#pragma unroll
    for (int i = 0; i < 4; ++i) { afA[i] = afN[i]; bfrA[i] = bfrN[i]; }
  }

  // ---- epilogue: C/D layout col=lane&15, row=(lane>>4)*4+j ----
  int col = lane & 15;
  int rb = (lane >> 4) * 4;
#pragma unroll
  for (int n = 0; n < 4; ++n) {
    int gn = bn * BN + wc * 64 + n * 16 + col;
    float bsv = bias[gn];
#pragma unroll
    for (int m = 0; m < 8; ++m) {
      int gm = bm * BM + wr * 128 + m * 16 + rb;
#pragma unroll
      for (int j = 0; j < 4; ++j)
        C[(size_t)(gm + j) * N_TOT + gn] = acc[m][n][j] + bsv;
    }
  }
}

__global__ void fill_kernel(float* p, int n, float v) {
  int stride = gridDim.x * blockDim.x;
  for (int i = blockIdx.x * blockDim.x + threadIdx.x; i < n; i += stride) p[i] = v;
}

extern "C" void kernel_launch(void* const* d_in, const int* in_sizes, int n_in,
                              void* d_out, int out_size, void* d_ws, size_t ws_size,
                              hipStream_t stream) {
  const float* x = (const float*)d_in[0];
  const int* wp = (const int*)d_in[1];
  const float* sc = (const float*)d_in[2];
  const float* bias = (const float*)d_in[3];
  float* out = (float*)d_out;

  size_t xb_bytes = (size_t)M_TOT * K_TOT * 2;  // 64 MiB
  size_t wb_bytes = (size_t)N_TOT * K_TOT * 2;  // 32 MiB
  if (ws_size < xb_bytes + wb_bytes) {
    fill_kernel<<<2048, 256, 0, stream>>>(out, out_size, 12345.0f);
    return;
  }
  u16* xb = (u16*)d_ws;
  u16* wb = (u16*)((char*)d_ws + xb_bytes);

  cvt_x_kernel<<<2048, 256, 0, stream>>>(x, xb, M_TOT * K_TOT / 8);
  dequant_w_kernel<<<2048, 256, 0, stream>>>(wp, sc, wb);
  gemm_bf16_kernel<<<(M_TOT / BM) * (N_TOT / BN), 512, 0, stream>>>(xb, wb, bias, out);
}

// Round 4
// 376.483 us; speedup vs baseline: 1.0545x; 1.0545x over previous
//
#include <hip/hip_runtime.h>
#include <stdint.h>

#define M_TOT 8192
#define K_TOT 4096
#define N_TOT 4096
#define GROUPQ 32

#define BM 256
#define BN 256
#define BK 32
#define NT (K_TOT / BK)   // 128 K-tiles

typedef __bf16 bf16x8 __attribute__((ext_vector_type(8)));
typedef float f32x16 __attribute__((ext_vector_type(16)));
typedef unsigned short u16;
typedef unsigned short u16x8 __attribute__((ext_vector_type(8)));

__device__ __forceinline__ u16 f2bf_rne(float f) {
  union { float f; uint32_t u; } v; v.f = f;
  uint32_t u = v.u;
  uint32_t r = (u + 0x7FFFu + ((u >> 16) & 1u)) >> 16;  // round-nearest-even
  return (u16)r;
}

// ---- prepass 1: x fp32 -> bf16 ----
__global__ void cvt_x_kernel(const float* __restrict__ x, u16* __restrict__ xb, int n8) {
  int stride = gridDim.x * blockDim.x;
  for (int i = blockIdx.x * blockDim.x + threadIdx.x; i < n8; i += stride) {
    const float4* p = (const float4*)(x + (size_t)i * 8);
    float4 a = p[0];
    float4 b = p[1];
    u16x8 o;
    o[0] = f2bf_rne(a.x); o[1] = f2bf_rne(a.y); o[2] = f2bf_rne(a.z); o[3] = f2bf_rne(a.w);
    o[4] = f2bf_rne(b.x); o[5] = f2bf_rne(b.y); o[6] = f2bf_rne(b.z); o[7] = f2bf_rne(b.w);
    *(u16x8*)(xb + (size_t)i * 8) = o;
  }
}

// ---- prepass 2: dequant packed nibbles -> bf16 W[N][K] row-major ----
__global__ void dequant_w_kernel(const int* __restrict__ wp, const float* __restrict__ sc,
                                 u16* __restrict__ wb) {
  const int KH = K_TOT / 2;
  const int total = N_TOT * KH / 8;
  int stride = gridDim.x * blockDim.x;
  for (int t = blockIdx.x * blockDim.x + threadIdx.x; t < total; t += stride) {
    int base = t * 8;
    int o = base >> 11;
    int ci = base & 2047;
    int e0 = ci * 2;
    float scale = sc[o * (K_TOT / GROUPQ) + (e0 >> 5)];
    int4 p0 = *(const int4*)(wp + base);
    int4 p1 = *(const int4*)(wp + base + 4);
    int v[8] = {p0.x, p0.y, p0.z, p0.w, p1.x, p1.y, p1.z, p1.w};
    u16x8 oA, oB;
#pragma unroll
    for (int j = 0; j < 8; ++j) {
      float lo = (float)((v[j] & 0xF) - 8) * scale;
      float hi = (float)(((v[j] >> 4) & 0xF) - 8) * scale;
      u16 lob = f2bf_rne(lo), hib = f2bf_rne(hi);
      if (j < 4) { oA[2 * j] = lob; oA[2 * j + 1] = hib; }
      else       { oB[2 * (j - 4)] = lob; oB[2 * (j - 4) + 1] = hib; }
    }
    u16* dst = wb + (size_t)o * K_TOT + e0;
    *(u16x8*)dst = oA;
    *(u16x8*)(dst + 8) = oB;
  }
}

// ---- main GEMM: 256x256 tile, BK=32, 8 waves (2Mx4N), 32x32x16 MFMA,
// 3-deep LDS ring (stage distance 2), ONE barrier per K-tile.
// Per tile: stage(t+2) || 12 ds_read_b128 -> lgkmcnt(0) -> 16 MFMA ->
// vmcnt(4) -> s_barrier.  Hazard proof: reads of slot bt drain at each
// wave's own lgkm0 before it reaches the barrier; iteration t+1's stage
// into bt is issued only after that barrier; vmcnt(4)+barrier orders t+1's
// gl_lds landings before any wave's t+1 reads. ----
__global__ __launch_bounds__(512, 2) void gemm_bf16_kernel(
    const u16* __restrict__ A, const u16* __restrict__ Bt,
    const float* __restrict__ bias, float* __restrict__ C) {
  __shared__ alignas(16) u16 sA[3][BM * BK];  // 3 x 16 KiB
  __shared__ alignas(16) u16 sB[3][BN * BK];  // 3 x 16 KiB  (96 KiB)

  const int ntn = N_TOT / BN;            // 16
  int wg = blockIdx.x, nwg = gridDim.x;  // 512, %8==0
  int cpx = nwg >> 3;
  int swz = (wg & 7) * cpx + (wg >> 3);  // bijective XCD swizzle
  int bm = swz / ntn, bn = swz % ntn;

  int tid = threadIdx.x, wid = tid >> 6, lane = tid & 63;
  int wr = wid >> 2, wc = wid & 3;       // 2M x 4N waves

  // ---- staging: gl_lds writes linear; source pre-swizzled so LDS[row]
  // chunk cl holds global chunk cl ^ ((row>>1)&3) ----
  int srow0 = (wid * 2) * 16 + (lane >> 2);
  int srow1 = (wid * 2 + 1) * 16 + (lane >> 2);
  int cl = lane & 3;
  int gch0 = (cl ^ ((srow0 >> 1) & 3)) * 8;
  int gch1 = (cl ^ ((srow1 >> 1) & 3)) * 8;
  const u16* aS0 = A + (size_t)(bm * BM + srow0) * K_TOT + gch0;
  const u16* aS1 = A + (size_t)(bm * BM + srow1) * K_TOT + gch1;
  const u16* bS0 = Bt + (size_t)(bn * BN + srow0) * K_TOT + gch0;
  const u16* bS1 = Bt + (size_t)(bn * BN + srow1) * K_TOT + gch1;
  int ldst0 = (wid * 2) * 16 * BK;
  int ldst1 = (wid * 2 + 1) * 16 * BK;

  auto stageA = [&](int ke, int b) {
    __builtin_amdgcn_global_load_lds(
        (const __attribute__((address_space(1))) uint32_t*)(aS0 + ke),
        (__attribute__((address_space(3))) uint32_t*)(&sA[b][ldst0]), 16, 0, 0);
    __builtin_amdgcn_global_load_lds(
        (const __attribute__((address_space(1))) uint32_t*)(aS1 + ke),
        (__attribute__((address_space(3))) uint32_t*)(&sA[b][ldst1]), 16, 0, 0);
  };
  auto stageB = [&](int ke, int b) {
    __builtin_amdgcn_global_load_lds(
        (const __attribute__((address_space(1))) uint32_t*)(bS0 + ke),
        (__attribute__((address_space(3))) uint32_t*)(&sB[b][ldst0]), 16, 0, 0);
    __builtin_amdgcn_global_load_lds(
        (const __attribute__((address_space(1))) uint32_t*)(bS1 + ke),
        (__attribute__((address_space(3))) uint32_t*)(&sB[b][ldst1]), 16, 0, 0);
  };

  // ---- reader offsets: 32x32x16 frag = row=lane&31, k=(lane>>5)*8;
  // chunk XOR'd by ((row>>1)&3) (same involution as staging) ----
  int rl = lane & 31;
  int kx = lane >> 5;
  int rx = (lane >> 1) & 3;              // == ((lane&31)>>1)&3
  int abase = (wr * 128 + rl) * BK;      // elem offset, + m*32*BK + chunk*8
  int bbase = (wc * 64 + rl) * BK;       // + n*32*BK + chunk*8
  int ch0 = ((0 * 2 + kx) ^ rx) * 8;     // kk=0 chunk
  int ch1 = ((1 * 2 + kx) ^ rx) * 8;     // kk=1 chunk

  f32x16 acc[4][2] = {};

  // prologue: stage tiles 0,1; wait tile 0 (tile 1's 4 stay in flight)
  stageA(0, 0); stageB(0, 0);
  stageA(BK, 1); stageB(BK, 1);
  asm volatile("s_waitcnt vmcnt(4)" ::: "memory");
  __builtin_amdgcn_s_barrier();

  for (int t = 0; t < NT; ++t) {
    int bt = t % 3;
    int bs = (t + 2) % 3;
    int ks = (t + 2) * BK;
    const u16* cA = sA[bt];
    const u16* cB = sB[bt];
    bool pf = (t + 2) < NT;

    if (pf) { stageA(ks, bs); stageB(ks, bs); }

    bf16x8 af[4][2], bfr[2][2];
#pragma unroll
    for (int m = 0; m < 4; ++m) {
      af[m][0] = *(const bf16x8*)(cA + abase + m * 32 * BK + ch0);
      af[m][1] = *(const bf16x8*)(cA + abase + m * 32 * BK + ch1);
    }
#pragma unroll
    for (int n = 0; n < 2; ++n) {
      bfr[n][0] = *(const bf16x8*)(cB + bbase + n * 32 * BK + ch0);
      bfr[n][1] = *(const bf16x8*)(cB + bbase + n * 32 * BK + ch1);
    }

    asm volatile("s_waitcnt lgkmcnt(0)" ::: "memory");
    __builtin_amdgcn_sched_barrier(0);
    __builtin_amdgcn_s_setprio(1);
#pragma unroll
    for (int kk = 0; kk < 2; ++kk)
#pragma unroll
      for (int m = 0; m < 4; ++m)
#pragma unroll
        for (int n = 0; n < 2; ++n)
          acc[m][n] = __builtin_amdgcn_mfma_f32_32x32x16_bf16(af[m][kk], bfr[n][kk], acc[m][n], 0, 0, 0);
    __builtin_amdgcn_s_setprio(0);

    if (pf) { asm volatile("s_waitcnt vmcnt(4)" ::: "memory"); }  // t+1 landed
    else    { asm volatile("s_waitcnt vmcnt(0)" ::: "memory"); }
    __builtin_amdgcn_s_barrier();
  }

  // ---- epilogue: 32x32 C/D layout col=lane&31, row=(reg&3)+8*(reg>>2)+4*(lane>>5) ----
  int colc = lane & 31;
  int rquad = (lane >> 5) * 4;
#pragma unroll
  for (int n = 0; n < 2; ++n) {
    int gn = bn * BN + wc * 64 + n * 32 + colc;
    float bsv = bias[gn];
#pragma unroll
    for (int m = 0; m < 4; ++m) {
      int gmb = bm * BM + wr * 128 + m * 32;
#pragma unroll
      for (int reg = 0; reg < 16; ++reg) {
        int row = (reg & 3) + 8 * (reg >> 2) + rquad;
        C[(size_t)(gmb + row) * N_TOT + gn] = acc[m][n][reg] + bsv;
      }
    }
  }
}

__global__ void fill_kernel(float* p, int n, float v) {
  int stride = gridDim.x * blockDim.x;
  for (int i = blockIdx.x * blockDim.x + threadIdx.x; i < n; i += stride) p[i] = v;
}

extern "C" void kernel_launch(void* const* d_in, const int* in_sizes, int n_in,
                              void* d_out, int out_size, void* d_ws, size_t ws_size,
                              hipStream_t stream) {
  const float* x = (const float*)d_in[0];
  const int* wp = (const int*)d_in[1];
  const float* sc = (const float*)d_in[2];
  const float* bias = (const float*)d_in[3];
  float* out = (float*)d_out;

  size_t xb_bytes = (size_t)M_TOT * K_TOT * 2;  // 64 MiB
  size_t wb_bytes = (size_t)N_TOT * K_TOT * 2;  // 32 MiB
  if (ws_size < xb_bytes + wb_bytes) {
    fill_kernel<<<2048, 256, 0, stream>>>(out, out_size, 12345.0f);
    return;
  }
  u16* xb = (u16*)d_ws;
  u16* wb = (u16*)((char*)d_ws + xb_bytes);

  cvt_x_kernel<<<2048, 256, 0, stream>>>(x, xb, M_TOT * K_TOT / 8);
  dequant_w_kernel<<<2048, 256, 0, stream>>>(wp, sc, wb);
  gemm_bf16_kernel<<<(M_TOT / BM) * (N_TOT / BN), 512, 0, stream>>>(xb, wb, bias, out);
}

// Round 5
// 372.891 us; speedup vs baseline: 1.0647x; 1.0096x over previous
//
#include <hip/hip_runtime.h>
#include <stdint.h>

#define M_TOT 8192
#define K_TOT 4096
#define N_TOT 4096
#define GROUPQ 32

#define BM 256
#define BN 256
#define BK 32
#define NT (K_TOT / BK)   // 128 K-tiles

typedef __bf16 bf16x8 __attribute__((ext_vector_type(8)));
typedef float f32x4 __attribute__((ext_vector_type(4)));
typedef unsigned short u16;
typedef unsigned short u16x8 __attribute__((ext_vector_type(8)));

__device__ __forceinline__ u16 f2bf_rne(float f) {
  union { float f; uint32_t u; } v; v.f = f;
  uint32_t u = v.u;
  uint32_t r = (u + 0x7FFFu + ((u >> 16) & 1u)) >> 16;  // round-nearest-even
  return (u16)r;
}

// ---- prepass 1: x fp32 -> bf16 ----
__global__ void cvt_x_kernel(const float* __restrict__ x, u16* __restrict__ xb, int n8) {
  int stride = gridDim.x * blockDim.x;
  for (int i = blockIdx.x * blockDim.x + threadIdx.x; i < n8; i += stride) {
    const float4* p = (const float4*)(x + (size_t)i * 8);
    float4 a = p[0];
    float4 b = p[1];
    u16x8 o;
    o[0] = f2bf_rne(a.x); o[1] = f2bf_rne(a.y); o[2] = f2bf_rne(a.z); o[3] = f2bf_rne(a.w);
    o[4] = f2bf_rne(b.x); o[5] = f2bf_rne(b.y); o[6] = f2bf_rne(b.z); o[7] = f2bf_rne(b.w);
    *(u16x8*)(xb + (size_t)i * 8) = o;
  }
}

// ---- prepass 2: dequant packed nibbles -> bf16 W[N][K] row-major ----
__global__ void dequant_w_kernel(const int* __restrict__ wp, const float* __restrict__ sc,
                                 u16* __restrict__ wb) {
  const int KH = K_TOT / 2;
  const int total = N_TOT * KH / 8;
  int stride = gridDim.x * blockDim.x;
  for (int t = blockIdx.x * blockDim.x + threadIdx.x; t < total; t += stride) {
    int base = t * 8;
    int o = base >> 11;
    int ci = base & 2047;
    int e0 = ci * 2;
    float scale = sc[o * (K_TOT / GROUPQ) + (e0 >> 5)];
    int4 p0 = *(const int4*)(wp + base);
    int4 p1 = *(const int4*)(wp + base + 4);
    int v[8] = {p0.x, p0.y, p0.z, p0.w, p1.x, p1.y, p1.z, p1.w};
    u16x8 oA, oB;
#pragma unroll
    for (int j = 0; j < 8; ++j) {
      float lo = (float)((v[j] & 0xF) - 8) * scale;
      float hi = (float)(((v[j] >> 4) & 0xF) - 8) * scale;
      u16 lob = f2bf_rne(lo), hib = f2bf_rne(hi);
      if (j < 4) { oA[2 * j] = lob; oA[2 * j + 1] = hib; }
      else       { oB[2 * (j - 4)] = lob; oB[2 * (j - 4) + 1] = hib; }
    }
    u16* dst = wb + (size_t)o * K_TOT + e0;
    *(u16x8*)dst = oA;
    *(u16x8*)(dst + 8) = oB;
  }
}

// ---- main GEMM: 256x256 tile, BK=32, 8 waves (2Mx4N), 16x16x32 MFMA,
// 3-deep LDS ring (stage distance 2), ONE barrier per K-tile, NO manual
// lgkm drains: compiler emits dependency-precise lgkmcnt(N) so fragment
// reads are serviced by the LDS pipe under earlier MFMAs (m97 precedent).
// Safety: every ds_read is consumed by a pre-barrier MFMA => data is in
// registers before the barrier; stage into that slot is issued only after
// the NEXT barrier; counted vmcnt(4)+barrier orders gl_lds landings. ----
__global__ __launch_bounds__(512, 2) void gemm_bf16_kernel(
    const u16* __restrict__ A, const u16* __restrict__ Bt,
    const float* __restrict__ bias, float* __restrict__ C) {
  __shared__ alignas(16) u16 sA[3][BM * BK];  // 3 x 16 KiB
  __shared__ alignas(16) u16 sB[3][BN * BK];  // 3 x 16 KiB  (96 KiB)

  const int ntn = N_TOT / BN;            // 16
  int wg = blockIdx.x, nwg = gridDim.x;  // 512, %8==0
  int cpx = nwg >> 3;
  int swz = (wg & 7) * cpx + (wg >> 3);  // bijective XCD swizzle
  int bm = swz / ntn, bn = swz % ntn;

  int tid = threadIdx.x, wid = tid >> 6, lane = tid & 63;
  int wr = wid >> 2, wc = wid & 3;       // 2M x 4N waves

  // ---- staging: gl_lds writes linear; source pre-swizzled so LDS[row]
  // chunk cl holds global chunk cl ^ ((row>>1)&3) ----
  int srow0 = (wid * 2) * 16 + (lane >> 2);
  int srow1 = (wid * 2 + 1) * 16 + (lane >> 2);
  int cl = lane & 3;
  int gch0 = (cl ^ ((srow0 >> 1) & 3)) * 8;
  int gch1 = (cl ^ ((srow1 >> 1) & 3)) * 8;
  const u16* aS0 = A + (size_t)(bm * BM + srow0) * K_TOT + gch0;
  const u16* aS1 = A + (size_t)(bm * BM + srow1) * K_TOT + gch1;
  const u16* bS0 = Bt + (size_t)(bn * BN + srow0) * K_TOT + gch0;
  const u16* bS1 = Bt + (size_t)(bn * BN + srow1) * K_TOT + gch1;
  int ldst0 = (wid * 2) * 16 * BK;
  int ldst1 = (wid * 2 + 1) * 16 * BK;

  auto stageA = [&](int ke, int b) {
    __builtin_amdgcn_global_load_lds(
        (const __attribute__((address_space(1))) uint32_t*)(aS0 + ke),
        (__attribute__((address_space(3))) uint32_t*)(&sA[b][ldst0]), 16, 0, 0);
    __builtin_amdgcn_global_load_lds(
        (const __attribute__((address_space(1))) uint32_t*)(aS1 + ke),
        (__attribute__((address_space(3))) uint32_t*)(&sA[b][ldst1]), 16, 0, 0);
  };
  auto stageB = [&](int ke, int b) {
    __builtin_amdgcn_global_load_lds(
        (const __attribute__((address_space(1))) uint32_t*)(bS0 + ke),
        (__attribute__((address_space(3))) uint32_t*)(&sB[b][ldst0]), 16, 0, 0);
    __builtin_amdgcn_global_load_lds(
        (const __attribute__((address_space(1))) uint32_t*)(bS1 + ke),
        (__attribute__((address_space(3))) uint32_t*)(&sB[b][ldst1]), 16, 0, 0);
  };

  // ---- reader offsets (round-2 proven 0-conflict pattern) ----
  int rr = lane & 15, rc = lane >> 4;
  int xorv = (rc ^ ((rr >> 1) & 3)) * 8;
  int abase = (wr * 128 + rr) * BK + xorv;
  int bbase = (wc * 64 + rr) * BK + xorv;

  f32x4 acc[8][4] = {};

  // prologue: stage tiles 0,1; wait tile 0 (tile 1's 4 stay in flight)
  stageA(0, 0); stageB(0, 0);
  stageA(BK, 1); stageB(BK, 1);
  asm volatile("s_waitcnt vmcnt(4)" ::: "memory");
  __builtin_amdgcn_s_barrier();

  for (int t = 0; t < NT; ++t) {
    int bt = t % 3;
    int bs = (t + 2) % 3;
    int ks = (t + 2) * BK;
    const u16* cA = sA[bt];
    const u16* cB = sB[bt];
    bool pf = (t + 2) < NT;

    if (pf) { stageA(ks, bs); stageB(ks, bs); }  // issue-early (vmem, not lgkm)

    // fragment reads: B first, then A; no manual drain -> compiler emits
    // counted lgkmcnt so af[m>0] reads are serviced under m=0..  MFMAs.
    bf16x8 bfr[4], af[8];
#pragma unroll
    for (int n = 0; n < 4; ++n) bfr[n] = *(const bf16x8*)(cB + bbase + n * 16 * BK);
#pragma unroll
    for (int m = 0; m < 8; ++m) af[m] = *(const bf16x8*)(cA + abase + m * 16 * BK);

    __builtin_amdgcn_s_setprio(1);
#pragma unroll
    for (int m = 0; m < 8; ++m)
#pragma unroll
      for (int n = 0; n < 4; ++n)
        acc[m][n] = __builtin_amdgcn_mfma_f32_16x16x32_bf16(af[m], bfr[n], acc[m][n], 0, 0, 0);
    __builtin_amdgcn_s_setprio(0);

    if (pf) { asm volatile("s_waitcnt vmcnt(4)" ::: "memory"); }  // t+1 landed
    else    { asm volatile("s_waitcnt vmcnt(0)" ::: "memory"); }
    __builtin_amdgcn_s_barrier();
  }

  // ---- epilogue: C/D layout col=lane&15, row=(lane>>4)*4+j ----
  int col = lane & 15;
  int rb = (lane >> 4) * 4;
#pragma unroll
  for (int n = 0; n < 4; ++n) {
    int gn = bn * BN + wc * 64 + n * 16 + col;
    float bsv = bias[gn];
#pragma unroll
    for (int m = 0; m < 8; ++m) {
      int gm = bm * BM + wr * 128 + m * 16 + rb;
#pragma unroll
      for (int j = 0; j < 4; ++j)
        C[(size_t)(gm + j) * N_TOT + gn] = acc[m][n][j] + bsv;
    }
  }
}

__global__ void fill_kernel(float* p, int n, float v) {
  int stride = gridDim.x * blockDim.x;
  for (int i = blockIdx.x * blockDim.x + threadIdx.x; i < n; i += stride) p[i] = v;
}

extern "C" void kernel_launch(void* const* d_in, const int* in_sizes, int n_in,
                              void* d_out, int out_size, void* d_ws, size_t ws_size,
                              hipStream_t stream) {
  const float* x = (const float*)d_in[0];
  const int* wp = (const int*)d_in[1];
  const float* sc = (const float*)d_in[2];
  const float* bias = (const float*)d_in[3];
  float* out = (float*)d_out;

  size_t xb_bytes = (size_t)M_TOT * K_TOT * 2;  // 64 MiB
  size_t wb_bytes = (size_t)N_TOT * K_TOT * 2;  // 32 MiB
  if (ws_size < xb_bytes + wb_bytes) {
    fill_kernel<<<2048, 256, 0, stream>>>(out, out_size, 12345.0f);
    return;
  }
  u16* xb = (u16*)d_ws;
  u16* wb = (u16*)((char*)d_ws + xb_bytes);

  cvt_x_kernel<<<2048, 256, 0, stream>>>(x, xb, M_TOT * K_TOT / 8);
  dequant_w_kernel<<<2048, 256, 0, stream>>>(wp, sc, wb);
  gemm_bf16_kernel<<<(M_TOT / BM) * (N_TOT / BN), 512, 0, stream>>>(xb, wb, bias, out);
}

// Round 6
// 279.399 us; speedup vs baseline: 1.4209x; 1.3346x over previous
//
#include <hip/hip_runtime.h>
#include <stdint.h>

#define M_TOT 8192
#define K_TOT 4096
#define N_TOT 4096
#define GROUPQ 32

#define BM 256
#define BN 256
#define BK 64
#define NT (K_TOT / BK)   // 64 K-tiles

typedef __bf16 bf16x8 __attribute__((ext_vector_type(8)));
typedef float f32x4 __attribute__((ext_vector_type(4)));
typedef unsigned short u16;
typedef unsigned short u16x8 __attribute__((ext_vector_type(8)));

__device__ __forceinline__ u16 f2bf_rne(float f) {
  union { float f; uint32_t u; } v; v.f = f;
  uint32_t u = v.u;
  uint32_t r = (u + 0x7FFFu + ((u >> 16) & 1u)) >> 16;  // round-nearest-even
  return (u16)r;
}

// ---- prepass 1: x fp32 -> bf16 ----
__global__ void cvt_x_kernel(const float* __restrict__ x, u16* __restrict__ xb, int n8) {
  int stride = gridDim.x * blockDim.x;
  for (int i = blockIdx.x * blockDim.x + threadIdx.x; i < n8; i += stride) {
    const float4* p = (const float4*)(x + (size_t)i * 8);
    float4 a = p[0];
    float4 b = p[1];
    u16x8 o;
    o[0] = f2bf_rne(a.x); o[1] = f2bf_rne(a.y); o[2] = f2bf_rne(a.z); o[3] = f2bf_rne(a.w);
    o[4] = f2bf_rne(b.x); o[5] = f2bf_rne(b.y); o[6] = f2bf_rne(b.z); o[7] = f2bf_rne(b.w);
    *(u16x8*)(xb + (size_t)i * 8) = o;
  }
}

// ---- prepass 2: dequant packed nibbles -> bf16 W[N][K] row-major ----
__global__ void dequant_w_kernel(const int* __restrict__ wp, const float* __restrict__ sc,
                                 u16* __restrict__ wb) {
  const int KH = K_TOT / 2;
  const int total = N_TOT * KH / 8;
  int stride = gridDim.x * blockDim.x;
  for (int t = blockIdx.x * blockDim.x + threadIdx.x; t < total; t += stride) {
    int base = t * 8;
    int o = base >> 11;
    int ci = base & 2047;
    int e0 = ci * 2;
    float scale = sc[o * (K_TOT / GROUPQ) + (e0 >> 5)];
    int4 p0 = *(const int4*)(wp + base);
    int4 p1 = *(const int4*)(wp + base + 4);
    int v[8] = {p0.x, p0.y, p0.z, p0.w, p1.x, p1.y, p1.z, p1.w};
    u16x8 oA, oB;
#pragma unroll
    for (int j = 0; j < 8; ++j) {
      float lo = (float)((v[j] & 0xF) - 8) * scale;
      float hi = (float)(((v[j] >> 4) & 0xF) - 8) * scale;
      u16 lob = f2bf_rne(lo), hib = f2bf_rne(hi);
      if (j < 4) { oA[2 * j] = lob; oA[2 * j + 1] = hib; }
      else       { oB[2 * (j - 4)] = lob; oB[2 * (j - 4) + 1] = hib; }
    }
    u16* dst = wb + (size_t)o * K_TOT + e0;
    *(u16x8*)dst = oA;
    *(u16x8*)(dst + 8) = oB;
  }
}

// ---- main GEMM: 256x256, BK=64, 8 waves (2Mx4N), 16x16x32 MFMA.
// 4 phases/K-tile (quadrants (mh,nh)=(00),(01),(10),(11)); each phase's
// ds_reads load the NEXT phase's fragments (parity regs a0/a1/b0/b1, no
// copies) -> LDS reads serviced under current MFMAs (compiler-counted lgkm).
// LDS: 2 bufs x 2 k-planes of the 0-conflict 64B-row layout (round-2 proven).
// Stage stream: 1 half-tile (2 gl_lds/thread) per phase; vmcnt(4) per tile
// boundary guarantees the next 4 phase-reads' data landed; lgkmcnt(0) once
// per tile (p4) + barriers make every stage-issue follow the target slot's
// last LDS read. ----
__global__ __launch_bounds__(512, 2) void gemm_bf16_kernel(
    const u16* __restrict__ A, const u16* __restrict__ Bt,
    const float* __restrict__ bias, float* __restrict__ C) {
  __shared__ alignas(16) u16 sL[65536];  // 128 KiB: A = [0,32768), B = [32768,65536)

  const int ntn = N_TOT / BN;            // 16
  int wg = blockIdx.x, nwg = gridDim.x;  // 512, %8==0
  int cpx = nwg >> 3;
  int swz = (wg & 7) * cpx + (wg >> 3);  // bijective XCD swizzle
  int bm = swz / ntn, bn = swz % ntn;

  int tid = threadIdx.x, wid = tid >> 6, lane = tid & 63;
  int wr = wid >> 2, wc = wid & 3;       // 2M x 4N waves
  const size_t K = K_TOT;

  // ---- staging addressing (per thread): half-tile = 128 rows x 64 cols,
  // stored as 2 k-planes of [128][32]; within a plane, LDS chunk c holds
  // global chunk c ^ ((row>>1)&3)  (round-2 involution) ----
  int rowS = tid >> 2;                   // 0..127
  int cgS = (tid & 3) ^ ((rowS >> 1) & 3);
  const u16* pA = A + ((size_t)(bm * 256 + (rowS >> 6) * 128 + (rowS & 63))) * K + cgS * 8;
  const u16* pB = Bt + ((size_t)(bn * 256 + (rowS >> 5) * 64 + (rowS & 31))) * K + cgS * 8;
  u16* sE = &sL[0];

  auto stA = [&](int T, int mh) {  // A half mh of tile T -> buf T&1 (2 gl_lds)
    int buf = T & 1;
    const u16* s = pA + (size_t)mh * 64 * K + T * 64;
    u16* d0 = sE + ((buf * 2 + 0) * 2 + mh) * 4096 + tid * 8;
    u16* d1 = sE + ((buf * 2 + 1) * 2 + mh) * 4096 + tid * 8;
    __builtin_amdgcn_global_load_lds(
        (const __attribute__((address_space(1))) uint32_t*)s,
        (__attribute__((address_space(3))) uint32_t*)d0, 16, 0, 0);
    __builtin_amdgcn_global_load_lds(
        (const __attribute__((address_space(1))) uint32_t*)(s + 32),
        (__attribute__((address_space(3))) uint32_t*)d1, 16, 0, 0);
  };
  auto stB = [&](int T, int nh) {
    int buf = T & 1;
    const u16* s = pB + (size_t)nh * 32 * K + T * 64;
    u16* d0 = sE + 32768 + ((buf * 2 + 0) * 2 + nh) * 4096 + tid * 8;
    u16* d1 = sE + 32768 + ((buf * 2 + 1) * 2 + nh) * 4096 + tid * 8;
    __builtin_amdgcn_global_load_lds(
        (const __attribute__((address_space(1))) uint32_t*)s,
        (__attribute__((address_space(3))) uint32_t*)d0, 16, 0, 0);
    __builtin_amdgcn_global_load_lds(
        (const __attribute__((address_space(1))) uint32_t*)(s + 32),
        (__attribute__((address_space(3))) uint32_t*)d1, 16, 0, 0);
  };

  // ---- reader addressing (0-conflict per plane, same involution) ----
  int rA = wr * 64 + (lane & 15);
  int cA = ((lane >> 4) ^ ((rA >> 1) & 3)) * 8;
  int rB = wc * 32 + (lane & 15);
  int cB = ((lane >> 4) ^ ((rB >> 1) & 3)) * 8;
  auto ldA = [&](int buf, int kk, int mh, int m3) {
    return *(const bf16x8*)(sE + ((buf * 2 + kk) * 2 + mh) * 4096 + (rA + m3 * 16) * 32 + cA);
  };
  auto ldB = [&](int buf, int kk, int nh, int n2) {
    return *(const bf16x8*)(sE + 32768 + ((buf * 2 + kk) * 2 + nh) * 4096 + (rB + n2 * 16) * 32 + cB);
  };

  f32x4 acc[8][4] = {};
  bf16x8 a0[4][2], a1[4][2], b0[2][2], b1[2][2];

  // ---- prologue: stage halves h=0..7 (tiles 0,1 complete), land tile 0+ ----
  stA(0, 0); stB(0, 0); stB(0, 1); stA(0, 1);
  stA(1, 0); stB(1, 0); stB(1, 1); stA(1, 1);
  asm volatile("s_waitcnt vmcnt(4)" ::: "memory");  // h<=5 landed (tile 0 full)
  __builtin_amdgcn_s_barrier();

  // prime: A0(0), B0(0)
#pragma unroll
  for (int m3 = 0; m3 < 4; ++m3)
#pragma unroll
    for (int kk = 0; kk < 2; ++kk) a0[m3][kk] = ldA(0, kk, 0, m3);
#pragma unroll
  for (int n2 = 0; n2 < 2; ++n2)
#pragma unroll
    for (int kk = 0; kk < 2; ++kk) b0[n2][kk] = ldB(0, kk, 0, n2);
  asm volatile("s_waitcnt lgkmcnt(0)" ::: "memory");
  __builtin_amdgcn_s_barrier();

  for (int t = 0; t < NT; ++t) {
    int buf = t & 1;
    int nbuf = buf ^ 1;
    bool st_ok = (t + 2 < NT);
    bool rd_ok = (t + 1 < NT);
    int Ts = t + 2;

    // ---- p1: read B1(t); stage A0(t+2); MFMA (A0,B0) -> acc[0..3][0,1] ----
#pragma unroll
    for (int n2 = 0; n2 < 2; ++n2)
#pragma unroll
      for (int kk = 0; kk < 2; ++kk) b1[n2][kk] = ldB(buf, kk, 1, n2);
    if (st_ok) stA(Ts, 0);
    __builtin_amdgcn_s_barrier();
    __builtin_amdgcn_s_setprio(1);
#pragma unroll
    for (int kk = 0; kk < 2; ++kk)
#pragma unroll
      for (int m3 = 0; m3 < 4; ++m3)
#pragma unroll
        for (int n2 = 0; n2 < 2; ++n2)
          acc[m3][n2] = __builtin_amdgcn_mfma_f32_16x16x32_bf16(a0[m3][kk], b0[n2][kk], acc[m3][n2], 0, 0, 0);
    __builtin_amdgcn_s_setprio(0);
    __builtin_amdgcn_s_barrier();

    // ---- p2: read A1(t); stage B0(t+2); MFMA (A0,B1) -> acc[0..3][2,3] ----
#pragma unroll
    for (int m3 = 0; m3 < 4; ++m3)
#pragma unroll
      for (int kk = 0; kk < 2; ++kk) a1[m3][kk] = ldA(buf, kk, 1, m3);
    if (st_ok) stB(Ts, 0);
    __builtin_amdgcn_s_barrier();
    __builtin_amdgcn_s_setprio(1);
#pragma unroll
    for (int kk = 0; kk < 2; ++kk)
#pragma unroll
      for (int m3 = 0; m3 < 4; ++m3)
#pragma unroll
        for (int n2 = 0; n2 < 2; ++n2)
          acc[m3][n2 + 2] = __builtin_amdgcn_mfma_f32_16x16x32_bf16(a0[m3][kk], b1[n2][kk], acc[m3][n2 + 2], 0, 0, 0);
    __builtin_amdgcn_s_setprio(0);
    __builtin_amdgcn_s_barrier();

    // ---- p3: read A0(t+1); stage B1(t+2); MFMA (A1,B0) -> acc[4..7][0,1] ----
    if (rd_ok) {
#pragma unroll
      for (int m3 = 0; m3 < 4; ++m3)
#pragma unroll
        for (int kk = 0; kk < 2; ++kk) a0[m3][kk] = ldA(nbuf, kk, 0, m3);
    }
    if (st_ok) stB(Ts, 1);
    __builtin_amdgcn_s_barrier();
    __builtin_amdgcn_s_setprio(1);
#pragma unroll
    for (int kk = 0; kk < 2; ++kk)
#pragma unroll
      for (int m3 = 0; m3 < 4; ++m3)
#pragma unroll
        for (int n2 = 0; n2 < 2; ++n2)
          acc[m3 + 4][n2] = __builtin_amdgcn_mfma_f32_16x16x32_bf16(a1[m3][kk], b0[n2][kk], acc[m3 + 4][n2], 0, 0, 0);
    __builtin_amdgcn_s_setprio(0);
    __builtin_amdgcn_s_barrier();

    // ---- p4: read B0(t+1); stage A1(t+2); MFMA (A1,B1) -> acc[4..7][2,3];
    //      tile boundary: lgkm0 (drain all this tile's reads) + vmcnt ----
    if (rd_ok) {
#pragma unroll
      for (int n2 = 0; n2 < 2; ++n2)
#pragma unroll
        for (int kk = 0; kk < 2; ++kk) b0[n2][kk] = ldB(nbuf, kk, 0, n2);
    }
    if (st_ok) stA(Ts, 1);
    __builtin_amdgcn_s_barrier();
    __builtin_amdgcn_s_setprio(1);
#pragma unroll
    for (int kk = 0; kk < 2; ++kk)
#pragma unroll
      for (int m3 = 0; m3 < 4; ++m3)
#pragma unroll
        for (int n2 = 0; n2 < 2; ++n2)
          acc[m3 + 4][n2 + 2] = __builtin_amdgcn_mfma_f32_16x16x32_bf16(a1[m3][kk], b1[n2][kk], acc[m3 + 4][n2 + 2], 0, 0, 0);
    __builtin_amdgcn_s_setprio(0);
    asm volatile("s_waitcnt lgkmcnt(0)" ::: "memory");
    if (t < NT - 2) { asm volatile("s_waitcnt vmcnt(4)" ::: "memory"); }
    else            { asm volatile("s_waitcnt vmcnt(0)" ::: "memory"); }
    __builtin_amdgcn_s_barrier();
  }

  asm volatile("s_waitcnt vmcnt(0)" ::: "memory");

  // ---- epilogue: C/D layout col=lane&15, row=(lane>>4)*4+j ----
  int col = lane & 15;
  int rb = (lane >> 4) * 4;
#pragma unroll
  for (int n = 0; n < 4; ++n) {
    int gn = bn * BN + wc * 64 + n * 16 + col;
    float bsv = bias[gn];
#pragma unroll
    for (int m = 0; m < 8; ++m) {
      int gm = bm * BM + wr * 128 + m * 16 + rb;
#pragma unroll
      for (int j = 0; j < 4; ++j)
        C[(size_t)(gm + j) * N_TOT + gn] = acc[m][n][j] + bsv;
    }
  }
}

__global__ void fill_kernel(float* p, int n, float v) {
  int stride = gridDim.x * blockDim.x;
  for (int i = blockIdx.x * blockDim.x + threadIdx.x; i < n; i += stride) p[i] = v;
}

extern "C" void kernel_launch(void* const* d_in, const int* in_sizes, int n_in,
                              void* d_out, int out_size, void* d_ws, size_t ws_size,
                              hipStream_t stream) {
  const float* x = (const float*)d_in[0];
  const int* wp = (const int*)d_in[1];
  const float* sc = (const float*)d_in[2];
  const float* bias = (const float*)d_in[3];
  float* out = (float*)d_out;

  size_t xb_bytes = (size_t)M_TOT * K_TOT * 2;  // 64 MiB
  size_t wb_bytes = (size_t)N_TOT * K_TOT * 2;  // 32 MiB
  if (ws_size < xb_bytes + wb_bytes) {
    fill_kernel<<<2048, 256, 0, stream>>>(out, out_size, 12345.0f);
    return;
  }
  u16* xb = (u16*)d_ws;
  u16* wb = (u16*)((char*)d_ws + xb_bytes);

  cvt_x_kernel<<<2048, 256, 0, stream>>>(x, xb, M_TOT * K_TOT / 8);
  dequant_w_kernel<<<2048, 256, 0, stream>>>(wp, sc, wb);
  gemm_bf16_kernel<<<(M_TOT / BM) * (N_TOT / BN), 512, 0, stream>>>(xb, wb, bias, out);
}

// Round 7
// 271.803 us; speedup vs baseline: 1.4606x; 1.0279x over previous
//
#include <hip/hip_runtime.h>
#include <stdint.h>

#define M_TOT 8192
#define K_TOT 4096
#define N_TOT 4096
#define GROUPQ 32

#define BM 256
#define BN 256
#define BK 64
#define NT (K_TOT / BK)   // 64 K-tiles

typedef __bf16 bf16x8 __attribute__((ext_vector_type(8)));
typedef float f32x4 __attribute__((ext_vector_type(4)));
typedef unsigned short u16;
typedef unsigned short u16x8 __attribute__((ext_vector_type(8)));

__device__ __forceinline__ u16 f2bf_rne(float f) {
  union { float f; uint32_t u; } v; v.f = f;
  uint32_t u = v.u;
  uint32_t r = (u + 0x7FFFu + ((u >> 16) & 1u)) >> 16;  // round-nearest-even
  return (u16)r;
}

// ---- prepass 1: x fp32 -> bf16 ----
__global__ void cvt_x_kernel(const float* __restrict__ x, u16* __restrict__ xb, int n8) {
  int stride = gridDim.x * blockDim.x;
  for (int i = blockIdx.x * blockDim.x + threadIdx.x; i < n8; i += stride) {
    const float4* p = (const float4*)(x + (size_t)i * 8);
    float4 a = p[0];
    float4 b = p[1];
    u16x8 o;
    o[0] = f2bf_rne(a.x); o[1] = f2bf_rne(a.y); o[2] = f2bf_rne(a.z); o[3] = f2bf_rne(a.w);
    o[4] = f2bf_rne(b.x); o[5] = f2bf_rne(b.y); o[6] = f2bf_rne(b.z); o[7] = f2bf_rne(b.w);
    *(u16x8*)(xb + (size_t)i * 8) = o;
  }
}

// ---- prepass 2: dequant packed nibbles -> bf16 W[N][K] row-major ----
__global__ void dequant_w_kernel(const int* __restrict__ wp, const float* __restrict__ sc,
                                 u16* __restrict__ wb) {
  const int KH = K_TOT / 2;
  const int total = N_TOT * KH / 8;
  int stride = gridDim.x * blockDim.x;
  for (int t = blockIdx.x * blockDim.x + threadIdx.x; t < total; t += stride) {
    int base = t * 8;
    int o = base >> 11;
    int ci = base & 2047;
    int e0 = ci * 2;
    float scale = sc[o * (K_TOT / GROUPQ) + (e0 >> 5)];
    int4 p0 = *(const int4*)(wp + base);
    int4 p1 = *(const int4*)(wp + base + 4);
    int v[8] = {p0.x, p0.y, p0.z, p0.w, p1.x, p1.y, p1.z, p1.w};
    u16x8 oA, oB;
#pragma unroll
    for (int j = 0; j < 8; ++j) {
      float lo = (float)((v[j] & 0xF) - 8) * scale;
      float hi = (float)(((v[j] >> 4) & 0xF) - 8) * scale;
      u16 lob = f2bf_rne(lo), hib = f2bf_rne(hi);
      if (j < 4) { oA[2 * j] = lob; oA[2 * j + 1] = hib; }
      else       { oB[2 * (j - 4)] = lob; oB[2 * (j - 4) + 1] = hib; }
    }
    u16* dst = wb + (size_t)o * K_TOT + e0;
    *(u16x8*)dst = oA;
    *(u16x8*)(dst + 8) = oB;
  }
}

// ---- main GEMM: 256x256, BK=64, 8 waves (2Mx4N), 16x16x32 MFMA.
// 4 phases/K-tile; each phase = {ds_read next-phase frags || stage || MFMA}.
// Barrier thinning (round-7): plane P read in phase p is consumed by phase
// p+1's MFMA (compiler lgkm drains the reads before that MFMA issues), so a
// barrier at END of p+1 suffices before P's overwrite-stage in p+2.
//   A0(t)/B0(t): read p3/p4 of t-1, drained by boundary lgkm0+barrier ->
//                p1/p2 stages need no mid-tile barrier.
//   B1(t): read p1, consumed p2 -> end-p2 barrier covers p3 stage.
//   A1(t): read p2, consumed p3 -> end-p3 barrier covers p4 stage.
// => 3 barriers/tile (end-p2, end-p3, boundary). vmcnt(4) per boundary
// guarantees the next tile's early-phase reads' data landed. ----
__global__ __launch_bounds__(512, 2) void gemm_bf16_kernel(
    const u16* __restrict__ A, const u16* __restrict__ Bt,
    const float* __restrict__ bias, float* __restrict__ C) {
  __shared__ alignas(16) u16 sL[65536];  // 128 KiB: A = [0,32768), B = [32768,65536)

  const int ntn = N_TOT / BN;            // 16
  int wg = blockIdx.x, nwg = gridDim.x;  // 512, %8==0
  int cpx = nwg >> 3;
  int swz = (wg & 7) * cpx + (wg >> 3);  // bijective XCD swizzle
  int bm = swz / ntn, bn = swz % ntn;

  int tid = threadIdx.x, wid = tid >> 6, lane = tid & 63;
  int wr = wid >> 2, wc = wid & 3;       // 2M x 4N waves
  const size_t K = K_TOT;

  // ---- staging addressing: half-tile = 128 rows x 64 cols, stored as two
  // k-planes of [128][32]; LDS chunk c holds global chunk c ^ ((row>>1)&3) ----
  int rowS = tid >> 2;                   // 0..127
  int cgS = (tid & 3) ^ ((rowS >> 1) & 3);
  const u16* pA = A + ((size_t)(bm * 256 + (rowS >> 6) * 128 + (rowS & 63))) * K + cgS * 8;
  const u16* pB = Bt + ((size_t)(bn * 256 + (rowS >> 5) * 64 + (rowS & 31))) * K + cgS * 8;
  u16* sE = &sL[0];

  auto stA = [&](int T, int mh) {  // A half mh of tile T -> buf T&1 (2 gl_lds)
    int buf = T & 1;
    const u16* s = pA + (size_t)mh * 64 * K + T * 64;
    u16* d0 = sE + ((buf * 2 + 0) * 2 + mh) * 4096 + tid * 8;
    u16* d1 = sE + ((buf * 2 + 1) * 2 + mh) * 4096 + tid * 8;
    __builtin_amdgcn_global_load_lds(
        (const __attribute__((address_space(1))) uint32_t*)s,
        (__attribute__((address_space(3))) uint32_t*)d0, 16, 0, 0);
    __builtin_amdgcn_global_load_lds(
        (const __attribute__((address_space(1))) uint32_t*)(s + 32),
        (__attribute__((address_space(3))) uint32_t*)d1, 16, 0, 0);
  };
  auto stB = [&](int T, int nh) {
    int buf = T & 1;
    const u16* s = pB + (size_t)nh * 32 * K + T * 64;
    u16* d0 = sE + 32768 + ((buf * 2 + 0) * 2 + nh) * 4096 + tid * 8;
    u16* d1 = sE + 32768 + ((buf * 2 + 1) * 2 + nh) * 4096 + tid * 8;
    __builtin_amdgcn_global_load_lds(
        (const __attribute__((address_space(1))) uint32_t*)s,
        (__attribute__((address_space(3))) uint32_t*)d0, 16, 0, 0);
    __builtin_amdgcn_global_load_lds(
        (const __attribute__((address_space(1))) uint32_t*)(s + 32),
        (__attribute__((address_space(3))) uint32_t*)d1, 16, 0, 0);
  };

  // ---- reader addressing (0-conflict per plane, same involution) ----
  int rA = wr * 64 + (lane & 15);
  int cA = ((lane >> 4) ^ ((rA >> 1) & 3)) * 8;
  int rB = wc * 32 + (lane & 15);
  int cB = ((lane >> 4) ^ ((rB >> 1) & 3)) * 8;
  auto ldA = [&](int buf, int kk, int mh, int m3) {
    return *(const bf16x8*)(sE + ((buf * 2 + kk) * 2 + mh) * 4096 + (rA + m3 * 16) * 32 + cA);
  };
  auto ldB = [&](int buf, int kk, int nh, int n2) {
    return *(const bf16x8*)(sE + 32768 + ((buf * 2 + kk) * 2 + nh) * 4096 + (rB + n2 * 16) * 32 + cB);
  };

  f32x4 acc[8][4] = {};
  bf16x8 a0[4][2], a1[4][2], b0[2][2], b1[2][2];

  // ---- prologue: stage halves (tiles 0,1), land all but newest 4 ----
  stA(0, 0); stB(0, 0); stB(0, 1); stA(0, 1);
  stA(1, 0); stB(1, 0); stB(1, 1); stA(1, 1);
  asm volatile("s_waitcnt vmcnt(4)" ::: "memory");
  __builtin_amdgcn_s_barrier();

  // prime: A0(0), B0(0)
#pragma unroll
  for (int m3 = 0; m3 < 4; ++m3)
#pragma unroll
    for (int kk = 0; kk < 2; ++kk) a0[m3][kk] = ldA(0, kk, 0, m3);
#pragma unroll
  for (int n2 = 0; n2 < 2; ++n2)
#pragma unroll
    for (int kk = 0; kk < 2; ++kk) b0[n2][kk] = ldB(0, kk, 0, n2);
  asm volatile("s_waitcnt lgkmcnt(0)" ::: "memory");
  __builtin_amdgcn_s_barrier();

  for (int t = 0; t < NT; ++t) {
    int buf = t & 1;
    int nbuf = buf ^ 1;
    bool st_ok = (t + 2 < NT);
    bool rd_ok = (t + 1 < NT);
    int Ts = t + 2;

    // ---- p1: read B1(t); stage A0(t+2); MFMA (A0,B0); NO barrier ----
#pragma unroll
    for (int n2 = 0; n2 < 2; ++n2)
#pragma unroll
      for (int kk = 0; kk < 2; ++kk) b1[n2][kk] = ldB(buf, kk, 1, n2);
    if (st_ok) stA(Ts, 0);
    __builtin_amdgcn_s_setprio(1);
#pragma unroll
    for (int kk = 0; kk < 2; ++kk)
#pragma unroll
      for (int m3 = 0; m3 < 4; ++m3)
#pragma unroll
        for (int n2 = 0; n2 < 2; ++n2)
          acc[m3][n2] = __builtin_amdgcn_mfma_f32_16x16x32_bf16(a0[m3][kk], b0[n2][kk], acc[m3][n2], 0, 0, 0);
    __builtin_amdgcn_s_setprio(0);

    // ---- p2: read A1(t); stage B0(t+2); MFMA (A0,B1); barrier (frees B1) ----
#pragma unroll
    for (int m3 = 0; m3 < 4; ++m3)
#pragma unroll
      for (int kk = 0; kk < 2; ++kk) a1[m3][kk] = ldA(buf, kk, 1, m3);
    if (st_ok) stB(Ts, 0);
    __builtin_amdgcn_s_setprio(1);
#pragma unroll
    for (int kk = 0; kk < 2; ++kk)
#pragma unroll
      for (int m3 = 0; m3 < 4; ++m3)
#pragma unroll
        for (int n2 = 0; n2 < 2; ++n2)
          acc[m3][n2 + 2] = __builtin_amdgcn_mfma_f32_16x16x32_bf16(a0[m3][kk], b1[n2][kk], acc[m3][n2 + 2], 0, 0, 0);
    __builtin_amdgcn_s_setprio(0);
    __builtin_amdgcn_s_barrier();

    // ---- p3: read A0(t+1); stage B1(t+2); MFMA (A1,B0); barrier (frees A1) ----
    if (rd_ok) {
#pragma unroll
      for (int m3 = 0; m3 < 4; ++m3)
#pragma unroll
        for (int kk = 0; kk < 2; ++kk) a0[m3][kk] = ldA(nbuf, kk, 0, m3);
    }
    if (st_ok) stB(Ts, 1);
    __builtin_amdgcn_s_setprio(1);
#pragma unroll
    for (int kk = 0; kk < 2; ++kk)
#pragma unroll
      for (int m3 = 0; m3 < 4; ++m3)
#pragma unroll
        for (int n2 = 0; n2 < 2; ++n2)
          acc[m3 + 4][n2] = __builtin_amdgcn_mfma_f32_16x16x32_bf16(a1[m3][kk], b0[n2][kk], acc[m3 + 4][n2], 0, 0, 0);
    __builtin_amdgcn_s_setprio(0);
    __builtin_amdgcn_s_barrier();

    // ---- p4: read B0(t+1); stage A1(t+2); MFMA (A1,B1); boundary:
    //      lgkm0 (drain this tile's remaining reads) + counted vmcnt + barrier ----
    if (rd_ok) {
#pragma unroll
      for (int n2 = 0; n2 < 2; ++n2)
#pragma unroll
        for (int kk = 0; kk < 2; ++kk) b0[n2][kk] = ldB(nbuf, kk, 0, n2);
    }
    if (st_ok) stA(Ts, 1);
    __builtin_amdgcn_s_setprio(1);
#pragma unroll
    for (int kk = 0; kk < 2; ++kk)
#pragma unroll
      for (int m3 = 0; m3 < 4; ++m3)
#pragma unroll
        for (int n2 = 0; n2 < 2; ++n2)
          acc[m3 + 4][n2 + 2] = __builtin_amdgcn_mfma_f32_16x16x32_bf16(a1[m3][kk], b1[n2][kk], acc[m3 + 4][n2 + 2], 0, 0, 0);
    __builtin_amdgcn_s_setprio(0);
    asm volatile("s_waitcnt lgkmcnt(0)" ::: "memory");
    if (t < NT - 2) { asm volatile("s_waitcnt vmcnt(4)" ::: "memory"); }
    else            { asm volatile("s_waitcnt vmcnt(0)" ::: "memory"); }
    __builtin_amdgcn_s_barrier();
  }

  asm volatile("s_waitcnt vmcnt(0)" ::: "memory");

  // ---- epilogue: C/D layout col=lane&15, row=(lane>>4)*4+j ----
  int col = lane & 15;
  int rb = (lane >> 4) * 4;
#pragma unroll
  for (int n = 0; n < 4; ++n) {
    int gn = bn * BN + wc * 64 + n * 16 + col;
    float bsv = bias[gn];
#pragma unroll
    for (int m = 0; m < 8; ++m) {
      int gm = bm * BM + wr * 128 + m * 16 + rb;
#pragma unroll
      for (int j = 0; j < 4; ++j)
        C[(size_t)(gm + j) * N_TOT + gn] = acc[m][n][j] + bsv;
    }
  }
}

__global__ void fill_kernel(float* p, int n, float v) {
  int stride = gridDim.x * blockDim.x;
  for (int i = blockIdx.x * blockDim.x + threadIdx.x; i < n; i += stride) p[i] = v;
}

extern "C" void kernel_launch(void* const* d_in, const int* in_sizes, int n_in,
                              void* d_out, int out_size, void* d_ws, size_t ws_size,
                              hipStream_t stream) {
  const float* x = (const float*)d_in[0];
  const int* wp = (const int*)d_in[1];
  const float* sc = (const float*)d_in[2];
  const float* bias = (const float*)d_in[3];
  float* out = (float*)d_out;

  size_t xb_bytes = (size_t)M_TOT * K_TOT * 2;  // 64 MiB
  size_t wb_bytes = (size_t)N_TOT * K_TOT * 2;  // 32 MiB
  if (ws_size < xb_bytes + wb_bytes) {
    fill_kernel<<<2048, 256, 0, stream>>>(out, out_size, 12345.0f);
    return;
  }
  u16* xb = (u16*)d_ws;
  u16* wb = (u16*)((char*)d_ws + xb_bytes);

  cvt_x_kernel<<<2048, 256, 0, stream>>>(x, xb, M_TOT * K_TOT / 8);
  dequant_w_kernel<<<2048, 256, 0, stream>>>(wp, sc, wb);
  gemm_bf16_kernel<<<(M_TOT / BM) * (N_TOT / BN), 512, 0, stream>>>(xb, wb, bias, out);
}